// Round 1
// baseline (312.520 us; speedup 1.0000x reference)
//
#include <hip/hip_runtime.h>
#include <hip/hip_bf16.h>

// Problem constants
#define BATCH 2048
#define TT 128
#define EE 192
#define HH 192
// SCALE = E^-0.5 = 192^-0.5
#define SCALE_F 0.07216878364870322f
#define LOG2E_F 1.4426950408889634f

typedef float f32x4 __attribute__((ext_vector_type(4)));
typedef short short8 __attribute__((ext_vector_type(8)));
typedef short short4v __attribute__((ext_vector_type(4)));

__device__ inline unsigned short f2bf(float x) {
  union { float f; unsigned u; } v; v.f = x;
  unsigned r = v.u + 0x7FFFu + ((v.u >> 16) & 1u);
  return (unsigned short)(r >> 16);
}

// ---- LDS layout (bytes) ----
// x_s / q_s / p_s region at 0:   [128][192+8] bf16, row stride 400 B (x, then Q, then P)
// k_s at 51200:                  [128][192+8] bf16, row stride 400 B  (K row-major [t][h])
// v_s at 102400:                 [192][128+8] bf16, row stride 272 B  (V transposed [h][t])
#define XO 0
#define XS 400
#define KO 51200
#define VO 102400
#define VS 272
#define PS 272
#define LDS_TOTAL 154624

// One projection: out[t][h] = sum_e x[t][e] * W[h][e], for this wave's
// 4 m-tiles (rows mh*64..mh*64+63) x 3 n-tiles (cols ns*48..ns*48+47).
// MFMA 16x16x32 bf16: A lane l: A[m=l&15][k=(l>>4)*8+j]; B lane l: B[k=(l>>4)*8+j][n=l&15];
// D lane l: D[m=(l>>4)*4+r][n=l&15].
__device__ inline void proj_mfma(const float* __restrict__ W, const char* xs,
                                 int ns, int mh, int lg, int lr, f32x4 acc[4][3]) {
  const f32x4 zero = {0.f, 0.f, 0.f, 0.f};
#pragma unroll
  for (int mt = 0; mt < 4; ++mt)
#pragma unroll
    for (int nt = 0; nt < 3; ++nt)
      acc[mt][nt] = zero;
#pragma unroll
  for (int kt = 0; kt < 6; ++kt) {
    int e0 = kt * 32 + lg * 8;
    short8 bfr[3];
#pragma unroll
    for (int nt = 0; nt < 3; ++nt) {
      int h = ns * 48 + nt * 16 + lr;
      const float* wp = W + h * EE + e0;
      float4 f0 = *(const float4*)wp;
      float4 f1 = *(const float4*)(wp + 4);
      short8 bb;
      bb[0] = (short)f2bf(f0.x); bb[1] = (short)f2bf(f0.y);
      bb[2] = (short)f2bf(f0.z); bb[3] = (short)f2bf(f0.w);
      bb[4] = (short)f2bf(f1.x); bb[5] = (short)f2bf(f1.y);
      bb[6] = (short)f2bf(f1.z); bb[7] = (short)f2bf(f1.w);
      bfr[nt] = bb;
    }
#pragma unroll
    for (int mt = 0; mt < 4; ++mt) {
      int t = mh * 64 + mt * 16 + lr;
      short8 a = *(const short8*)(xs + t * XS + e0 * 2);
#pragma unroll
      for (int nt = 0; nt < 3; ++nt)
        acc[mt][nt] = __builtin_amdgcn_mfma_f32_16x16x32_bf16(a, bfr[nt], acc[mt][nt], 0, 0, 0);
    }
  }
}

__global__ __launch_bounds__(512, 2)
void head_kernel(const float* __restrict__ x, const float* __restrict__ Wq,
                 const float* __restrict__ Wk, const float* __restrict__ Wv,
                 float* __restrict__ out) {
  extern __shared__ char smem[];
  const int b = blockIdx.x;
  const int tid = threadIdx.x;
  const int wid = tid >> 6, lane = tid & 63;
  const int lg = lane >> 4, lr = lane & 15;
  const int ns = wid >> 1, mh = wid & 1;  // weight n-slab (0..3), m-half (0..1)

  // ---- Phase 1: stage x[b] -> LDS as bf16 ----
  const float4* xb4 = (const float4*)(x + (size_t)b * (TT * EE));
#pragma unroll
  for (int i = 0; i < 12; ++i) {
    int fi = tid + i * 512;          // float4 index, 6144 total
    float4 f = xb4[fi];
    int row = fi / 48, c4 = fi % 48; // 48 float4 per row of 192
    short4v h4;
    h4[0] = (short)f2bf(f.x); h4[1] = (short)f2bf(f.y);
    h4[2] = (short)f2bf(f.z); h4[3] = (short)f2bf(f.w);
    *(short4v*)(smem + XO + row * XS + c4 * 8) = h4;
  }
  __syncthreads();

  f32x4 acc[4][3];

  // ---- K projection -> k_s row-major [t][h] ----
  proj_mfma(Wk, smem + XO, ns, mh, lg, lr, acc);
#pragma unroll
  for (int mt = 0; mt < 4; ++mt)
#pragma unroll
    for (int nt = 0; nt < 3; ++nt) {
      int h = ns * 48 + nt * 16 + lr;
#pragma unroll
      for (int r = 0; r < 4; ++r) {
        int t = mh * 64 + mt * 16 + lg * 4 + r;
        *(unsigned short*)(smem + KO + t * XS + h * 2) = f2bf(acc[mt][nt][r]);
      }
    }

  // ---- V projection -> v_s transposed [h][t] (4 consecutive t per lane: b64 pack) ----
  proj_mfma(Wv, smem + XO, ns, mh, lg, lr, acc);
#pragma unroll
  for (int mt = 0; mt < 4; ++mt)
#pragma unroll
    for (int nt = 0; nt < 3; ++nt) {
      int h = ns * 48 + nt * 16 + lr;
      int t0 = mh * 64 + mt * 16 + lg * 4;
      short4v p;
      p[0] = (short)f2bf(acc[mt][nt][0]); p[1] = (short)f2bf(acc[mt][nt][1]);
      p[2] = (short)f2bf(acc[mt][nt][2]); p[3] = (short)f2bf(acc[mt][nt][3]);
      *(short4v*)(smem + VO + h * VS + t0 * 2) = p;
    }

  // ---- Q projection -> q_s (reuses x region after barrier) ----
  proj_mfma(Wq, smem + XO, ns, mh, lg, lr, acc);
  __syncthreads();  // all waves done reading x_s
#pragma unroll
  for (int mt = 0; mt < 4; ++mt)
#pragma unroll
    for (int nt = 0; nt < 3; ++nt) {
      int h = ns * 48 + nt * 16 + lr;
#pragma unroll
      for (int r = 0; r < 4; ++r) {
        int t = mh * 64 + mt * 16 + lg * 4 + r;
        *(unsigned short*)(smem + XO + t * XS + h * 2) = f2bf(acc[mt][nt][r]);
      }
    }
  __syncthreads();  // q_s / k_s / v_s visible to all

  // ---- Phase 3: attention. Wave owns q rows qt*16 .. qt*16+15 ----
  const int qt = wid;
  f32x4 s[8];
  const f32x4 zero = {0.f, 0.f, 0.f, 0.f};
#pragma unroll
  for (int nt = 0; nt < 8; ++nt) s[nt] = zero;
#pragma unroll
  for (int kt = 0; kt < 6; ++kt) {
    int e0 = kt * 32 + lg * 8;
    short8 a = *(const short8*)(smem + XO + (qt * 16 + lr) * XS + e0 * 2);  // Q
#pragma unroll
    for (int nt = 0; nt < 8; ++nt) {
      short8 bb = *(const short8*)(smem + KO + (nt * 16 + lr) * XS + e0 * 2);  // K
      s[nt] = __builtin_amdgcn_mfma_f32_16x16x32_bf16(a, bb, s[nt], 0, 0, 0);
    }
  }

  // ---- softmax (full row resident; causal mask; 16-lane group reduction) ----
  const float CSC = SCALE_F * LOG2E_F;
  float pv[4][8];
  float rinv[4];
#pragma unroll
  for (int r = 0; r < 4; ++r) {
    int q = qt * 16 + lg * 4 + r;
    float mx = -INFINITY;
#pragma unroll
    for (int nt = 0; nt < 8; ++nt) {
      int c = nt * 16 + lr;
      float v = s[nt][r] * CSC;
      v = (c <= q) ? v : -INFINITY;
      pv[r][nt] = v;
      mx = fmaxf(mx, v);
    }
    mx = fmaxf(mx, __shfl_xor(mx, 1));
    mx = fmaxf(mx, __shfl_xor(mx, 2));
    mx = fmaxf(mx, __shfl_xor(mx, 4));
    mx = fmaxf(mx, __shfl_xor(mx, 8));
    float sum = 0.f;
#pragma unroll
    for (int nt = 0; nt < 8; ++nt) {
      float p = exp2f(pv[r][nt] - mx);
      pv[r][nt] = p;
      sum += p;
    }
    sum += __shfl_xor(sum, 1);
    sum += __shfl_xor(sum, 2);
    sum += __shfl_xor(sum, 4);
    sum += __shfl_xor(sum, 8);
    rinv[r] = 1.0f / sum;
  }
  __syncthreads();  // all QK^T reads of q_s done before overwriting with P

  // ---- write normalized P (bf16) into p_s (x/q region, stride 272) ----
#pragma unroll
  for (int r = 0; r < 4; ++r) {
    int q = qt * 16 + lg * 4 + r;
#pragma unroll
    for (int nt = 0; nt < 8; ++nt)
      *(unsigned short*)(smem + XO + q * PS + (nt * 16 + lr) * 2) = f2bf(pv[r][nt] * rinv[r]);
  }
  __syncthreads();

  // ---- PV: out[q][h] = sum_t P[q][t] V[t][h] ----
  f32x4 o[12];
#pragma unroll
  for (int nt = 0; nt < 12; ++nt) o[nt] = zero;
#pragma unroll
  for (int kt = 0; kt < 4; ++kt) {
    int t0 = kt * 32 + lg * 8;
    short8 a = *(const short8*)(smem + XO + (qt * 16 + lr) * PS + t0 * 2);  // P
#pragma unroll
    for (int nt = 0; nt < 12; ++nt) {
      short8 bb = *(const short8*)(smem + VO + (nt * 16 + lr) * VS + t0 * 2);  // V^T
      o[nt] = __builtin_amdgcn_mfma_f32_16x16x32_bf16(a, bb, o[nt], 0, 0, 0);
    }
  }

  // ---- store out fp32 ----
  float* ob = out + (size_t)b * (TT * HH);
#pragma unroll
  for (int nt = 0; nt < 12; ++nt)
#pragma unroll
    for (int r = 0; r < 4; ++r) {
      int q = qt * 16 + lg * 4 + r;
      ob[q * HH + nt * 16 + lr] = o[nt][r];
    }
}

extern "C" void kernel_launch(void* const* d_in, const int* in_sizes, int n_in,
                              void* d_out, int out_size, void* d_ws, size_t ws_size,
                              hipStream_t stream) {
  const float* x  = (const float*)d_in[0];
  const float* Wq = (const float*)d_in[1];
  const float* Wk = (const float*)d_in[2];
  const float* Wv = (const float*)d_in[3];
  float* out = (float*)d_out;
  int Bn = in_sizes[0] / (TT * EE);
  hipLaunchKernelGGL(head_kernel, dim3(Bn), dim3(512), LDS_TOTAL, stream,
                     x, Wq, Wk, Wv, out);
}